// Round 1
// baseline (482.511 us; speedup 1.0000x reference)
//
#include <hip/hip_runtime.h>
#include <hip/hip_bf16.h>

#define E_DIM 1024
#define NHEAD 16
#define HDIM  64
#define BATCH 4
#define SEQ   2048

typedef __attribute__((ext_vector_type(8))) short bf16x8;
typedef __attribute__((ext_vector_type(4))) float f32x4;

static __device__ __forceinline__ unsigned short bits_of(__hip_bfloat16 h) {
    return *reinterpret_cast<unsigned short*>(&h);
}

// ---------------- cast fp32 -> bf16, 4 elems/thread ----------------
__global__ void cast_kernel(const float* __restrict__ in,
                            __hip_bfloat16* __restrict__ out, int n4) {
    int i = blockIdx.x * blockDim.x + threadIdx.x;
    if (i < n4) {
        float4 v = reinterpret_cast<const float4*>(in)[i];
        ushort4 u;
        u.x = bits_of(__float2bfloat16(v.x));
        u.y = bits_of(__float2bfloat16(v.y));
        u.z = bits_of(__float2bfloat16(v.z));
        u.w = bits_of(__float2bfloat16(v.w));
        reinterpret_cast<ushort4*>(out)[i] = u;
    }
}

// ---------------- GEMM: C[m][n] = sum_k A[m][k] * Bw[n][k] ----------------
// 128x128 tile, BK=32, 256 threads (4 waves in 2x2), 16x16x32 bf16 MFMA.
template<int OUT_BF16>
__global__ __launch_bounds__(256) void gemm_bt(
    const __hip_bfloat16* __restrict__ A,
    const __hip_bfloat16* __restrict__ Bw,
    void* __restrict__ Cv, int M, int N, int K) {
    __shared__ __hip_bfloat16 As[128][40];  // +8 pad: conflict-light, 16B-aligned rows
    __shared__ __hip_bfloat16 Bs[128][40];

    const int t = threadIdx.x;
    const int mBase = blockIdx.y * 128, nBase = blockIdx.x * 128;
    const int lane = t & 63, w = t >> 6;
    const int wr = (w >> 1) * 64, wc = (w & 1) * 64;
    const int lr = lane & 15, lk = (lane >> 4) * 8;
    const int r0 = t >> 2, c80 = (t & 3) * 8;  // staging: row, col8 of first chunk

    f32x4 acc[4][4];
#pragma unroll
    for (int i = 0; i < 4; ++i)
#pragma unroll
        for (int j = 0; j < 4; ++j) acc[i][j] = (f32x4){0.f, 0.f, 0.f, 0.f};

    for (int kt = 0; kt < K; kt += 32) {
        __syncthreads();
#pragma unroll
        for (int it = 0; it < 2; ++it) {
            int r = r0 + it * 64;
            *reinterpret_cast<uint4*>(&As[r][c80]) =
                *reinterpret_cast<const uint4*>(A + (size_t)(mBase + r) * K + kt + c80);
            *reinterpret_cast<uint4*>(&Bs[r][c80]) =
                *reinterpret_cast<const uint4*>(Bw + (size_t)(nBase + r) * K + kt + c80);
        }
        __syncthreads();
        bf16x8 af[4], bfr[4];
#pragma unroll
        for (int i = 0; i < 4; ++i) {
            af[i]  = *reinterpret_cast<const bf16x8*>(&As[wr + i * 16 + lr][lk]);
            bfr[i] = *reinterpret_cast<const bf16x8*>(&Bs[wc + i * 16 + lr][lk]);
        }
#pragma unroll
        for (int i = 0; i < 4; ++i)
#pragma unroll
            for (int j = 0; j < 4; ++j)
                acc[i][j] = __builtin_amdgcn_mfma_f32_16x16x32_bf16(
                    af[i], bfr[j], acc[i][j], 0, 0, 0);
    }

    // C/D layout: col = lane&15, row = (lane>>4)*4 + v  [measured m89/m91]
#pragma unroll
    for (int i = 0; i < 4; ++i)
#pragma unroll
        for (int j = 0; j < 4; ++j)
#pragma unroll
            for (int v = 0; v < 4; ++v) {
                const int row = mBase + wr + i * 16 + (lane >> 4) * 4 + v;
                const int col = nBase + wc + j * 16 + lr;
                if (OUT_BF16)
                    ((__hip_bfloat16*)Cv)[(size_t)row * N + col] =
                        __float2bfloat16(acc[i][j][v]);
                else
                    ((float*)Cv)[(size_t)row * N + col] = acc[i][j][v];
            }
}

// ---------------- flash attention ----------------
// grid (S/64, H, B). 4 waves; wave w owns q-rows [qb*64+w*16, +16).
// K staged [32 keys][64 d] in LDS; V staged transposed VT[64 d][32 keys].
// P round-trips through per-wave LDS to convert C-layout -> A-fragment layout.
__global__ __launch_bounds__(256) void attn_kernel(
    const __hip_bfloat16* __restrict__ Q,
    const __hip_bfloat16* __restrict__ K,
    const __hip_bfloat16* __restrict__ V,
    __hip_bfloat16* __restrict__ O) {
    __shared__ __hip_bfloat16 Ks[32][80];      // stride 160B (16B-aligned)
    __shared__ __hip_bfloat16 VT[64][40];      // stride 80B
    __shared__ __hip_bfloat16 Ps[4][16][40];   // per-wave P tile

    const int qb = blockIdx.x;
    const int h  = blockIdx.y;
    const int b  = blockIdx.z;
    const size_t base = ((size_t)b * SEQ) * E_DIM + (size_t)h * HDIM;
    const __hip_bfloat16* Qg = Q + base;
    const __hip_bfloat16* Kg = K + base;
    const __hip_bfloat16* Vg = V + base;
    __hip_bfloat16* Og = O + base;

    const int t = threadIdx.x;
    const int w = t >> 6, lane = t & 63;
    const int lr = lane & 15, lk = (lane >> 4) * 8;
    const int qw0 = qb * 64 + w * 16;

    // Q fragments held in registers for the whole kernel (A-frag: row=lane&15)
    bf16x8 aq[2];
#pragma unroll
    for (int kk = 0; kk < 2; ++kk)
        aq[kk] = *reinterpret_cast<const bf16x8*>(
            Qg + (size_t)(qw0 + lr) * E_DIM + kk * 32 + lk);

    float m_run[4], l_run[4];
    f32x4 o_acc[4];
#pragma unroll
    for (int v = 0; v < 4; ++v) { m_run[v] = -1e30f; l_run[v] = 0.f; }
#pragma unroll
    for (int db = 0; db < 4; ++db) o_acc[db] = (f32x4){0.f, 0.f, 0.f, 0.f};

    const int nt = qb * 2 + 2;              // causal: keys up to qb*64+63
    const int skey = t & 31, sd = (t >> 5) * 8;

    for (int kt = 0; kt < nt; ++kt) {
        const int k0 = kt * 32;
        __syncthreads();   // previous iteration's reads of Ks/VT done
        // stage K tile (coalesced within 8-lane groups per row)
        *reinterpret_cast<uint4*>(&Ks[skey][sd]) =
            *reinterpret_cast<const uint4*>(Kg + (size_t)(k0 + skey) * E_DIM + sd);
        // stage V transposed
        {
            bf16x8 vv = *reinterpret_cast<const bf16x8*>(
                Vg + (size_t)(k0 + skey) * E_DIM + sd);
            const __hip_bfloat16* vp = reinterpret_cast<const __hip_bfloat16*>(&vv);
#pragma unroll
            for (int j = 0; j < 8; ++j) VT[sd + j][skey] = vp[j];
        }
        __syncthreads();

        // QK^T: s[g] = 16q x 16k scores for key group g
        f32x4 s[2];
        s[0] = (f32x4){0.f, 0.f, 0.f, 0.f};
        s[1] = (f32x4){0.f, 0.f, 0.f, 0.f};
#pragma unroll
        for (int g = 0; g < 2; ++g)
#pragma unroll
            for (int kk = 0; kk < 2; ++kk) {
                bf16x8 bk = *reinterpret_cast<const bf16x8*>(
                    &Ks[g * 16 + lr][kk * 32 + lk]);
                s[g] = __builtin_amdgcn_mfma_f32_16x16x32_bf16(aq[kk], bk, s[g], 0, 0, 0);
            }

        // online softmax (per accum-row v; rows replicated across 16-lane group)
#pragma unroll
        for (int v = 0; v < 4; ++v) {
            const int qrow = qw0 + (lane >> 4) * 4 + v;
            float s0 = s[0][v] * 0.03125f;   // 1/sqrt(E) = 1/32
            float s1 = s[1][v] * 0.03125f;
            if (k0 + lr > qrow)      s0 = -1e30f;
            if (k0 + 16 + lr > qrow) s1 = -1e30f;
            float mx = fmaxf(s0, s1);
#pragma unroll
            for (int off = 1; off < 16; off <<= 1)
                mx = fmaxf(mx, __shfl_xor(mx, off));
            const float mn   = fmaxf(m_run[v], mx);
            const float corr = __expf(m_run[v] - mn);
            const float p0 = __expf(s0 - mn);
            const float p1 = __expf(s1 - mn);
            float rs = p0 + p1;
#pragma unroll
            for (int off = 1; off < 16; off <<= 1)
                rs += __shfl_xor(rs, off);
            l_run[v] = l_run[v] * corr + rs;
            m_run[v] = mn;
#pragma unroll
            for (int db = 0; db < 4; ++db) o_acc[db][v] *= corr;
            const int prow = (lane >> 4) * 4 + v;
            Ps[w][prow][lr]      = __float2bfloat16(p0);
            Ps[w][prow][16 + lr] = __float2bfloat16(p1);
        }
        __syncthreads();   // make P (and keep VT) visible/ordered before PV

        // PV: o_acc[db] += P(16x32) * V(32x16)
        bf16x8 pa = *reinterpret_cast<const bf16x8*>(&Ps[w][lr][lk]);
#pragma unroll
        for (int db = 0; db < 4; ++db) {
            bf16x8 bv = *reinterpret_cast<const bf16x8*>(&VT[db * 16 + lr][lk]);
            o_acc[db] = __builtin_amdgcn_mfma_f32_16x16x32_bf16(pa, bv, o_acc[db], 0, 0, 0);
        }
    }

    // epilogue: normalize and store bf16
#pragma unroll
    for (int v = 0; v < 4; ++v) {
        const float inv = 1.f / l_run[v];
        const size_t row = (size_t)(qw0 + (lane >> 4) * 4 + v) * E_DIM;
#pragma unroll
        for (int db = 0; db < 4; ++db)
            Og[row + db * 16 + lr] = __float2bfloat16(o_acc[db][v] * inv);
    }
}

// ---------------- launch ----------------
extern "C" void kernel_launch(void* const* d_in, const int* in_sizes, int n_in,
                              void* d_out, int out_size, void* d_ws, size_t ws_size,
                              hipStream_t stream) {
    const float* x  = (const float*)d_in[0];
    const float* wq = (const float*)d_in[1];
    const float* wk = (const float*)d_in[2];
    const float* wv = (const float*)d_in[3];
    const float* wo = (const float*)d_in[4];

    const size_t SZ_X = (size_t)BATCH * SEQ * E_DIM;  // 8388608
    const size_t SZ_W = (size_t)E_DIM * E_DIM;        // 1048576

    char* p = (char*)d_ws;
    __hip_bfloat16* xb   = (__hip_bfloat16*)p; p += SZ_X * 2;
    __hip_bfloat16* wqb  = (__hip_bfloat16*)p; p += SZ_W * 2;
    __hip_bfloat16* wkb  = (__hip_bfloat16*)p; p += SZ_W * 2;
    __hip_bfloat16* wvb  = (__hip_bfloat16*)p; p += SZ_W * 2;
    __hip_bfloat16* wob  = (__hip_bfloat16*)p; p += SZ_W * 2;
    __hip_bfloat16* Qb   = (__hip_bfloat16*)p; p += SZ_X * 2;
    __hip_bfloat16* Kb   = (__hip_bfloat16*)p; p += SZ_X * 2;
    __hip_bfloat16* Vb   = (__hip_bfloat16*)p; p += SZ_X * 2;
    __hip_bfloat16* attb = (__hip_bfloat16*)p; p += SZ_X * 2;

    // casts
    cast_kernel<<<(int)(SZ_X / 4 / 256), 256, 0, stream>>>(x, xb, (int)(SZ_X / 4));
    cast_kernel<<<(int)(SZ_W / 4 / 256), 256, 0, stream>>>(wq, wqb, (int)(SZ_W / 4));
    cast_kernel<<<(int)(SZ_W / 4 / 256), 256, 0, stream>>>(wk, wkb, (int)(SZ_W / 4));
    cast_kernel<<<(int)(SZ_W / 4 / 256), 256, 0, stream>>>(wv, wvb, (int)(SZ_W / 4));
    cast_kernel<<<(int)(SZ_W / 4 / 256), 256, 0, stream>>>(wo, wob, (int)(SZ_W / 4));

    const int M = BATCH * SEQ;  // 8192
    dim3 gg(E_DIM / 128, M / 128);  // (8, 64)
    gemm_bt<1><<<gg, 256, 0, stream>>>(xb, wqb, Qb, M, E_DIM, E_DIM);
    gemm_bt<1><<<gg, 256, 0, stream>>>(xb, wkb, Kb, M, E_DIM, E_DIM);
    gemm_bt<1><<<gg, 256, 0, stream>>>(xb, wvb, Vb, M, E_DIM, E_DIM);

    attn_kernel<<<dim3(SEQ / 64, NHEAD, BATCH), 256, 0, stream>>>(Qb, Kb, Vb, attb);

    gemm_bt<0><<<gg, 256, 0, stream>>>(attb, wob, d_out, M, E_DIM, E_DIM);
}

// Round 2
// 269.020 us; speedup vs baseline: 1.7936x; 1.7936x over previous
//
#include <hip/hip_runtime.h>
#include <hip/hip_bf16.h>

#define E_DIM 1024
#define NHEAD 16
#define HDIM  64
#define BATCH 4
#define SEQ   2048
#define RQKV  (3 * E_DIM)

typedef __attribute__((ext_vector_type(8))) short bf16x8;
typedef __attribute__((ext_vector_type(4))) float f32x4;
typedef __attribute__((ext_vector_type(16))) float f32x16;

static __device__ __forceinline__ unsigned short bits_of(__hip_bfloat16 h) {
    return *reinterpret_cast<unsigned short*>(&h);
}

static __device__ __forceinline__ void gload_lds16(const void* g, void* l) {
    __builtin_amdgcn_global_load_lds(
        (__attribute__((address_space(1))) void*)g,
        (__attribute__((address_space(3))) void*)l, 16, 0, 0);
}

// ---------------- cast fp32 -> bf16, 4 elems/thread ----------------
__global__ void cast_kernel(const float* __restrict__ in,
                            __hip_bfloat16* __restrict__ out, int n4) {
    int i = blockIdx.x * blockDim.x + threadIdx.x;
    if (i < n4) {
        float4 v = reinterpret_cast<const float4*>(in)[i];
        ushort4 u;
        u.x = bits_of(__float2bfloat16(v.x));
        u.y = bits_of(__float2bfloat16(v.y));
        u.z = bits_of(__float2bfloat16(v.z));
        u.w = bits_of(__float2bfloat16(v.w));
        reinterpret_cast<ushort4*>(out)[i] = u;
    }
}

// ---------------- GEMM: C[m][n] = sum_k A[m][k] * Bw[n][k] ----------------
template<int OUT_BF16>
__global__ __launch_bounds__(256) void gemm_bt(
    const __hip_bfloat16* __restrict__ A,
    const __hip_bfloat16* __restrict__ Bw,
    void* __restrict__ Cv, int M, int N, int K) {
    __shared__ __hip_bfloat16 As[128][40];
    __shared__ __hip_bfloat16 Bs[128][40];

    const int t = threadIdx.x;
    const int mBase = blockIdx.y * 128, nBase = blockIdx.x * 128;
    const int lane = t & 63, w = t >> 6;
    const int wr = (w >> 1) * 64, wc = (w & 1) * 64;
    const int lr = lane & 15, lk = (lane >> 4) * 8;
    const int r0 = t >> 2, c80 = (t & 3) * 8;

    f32x4 acc[4][4];
#pragma unroll
    for (int i = 0; i < 4; ++i)
#pragma unroll
        for (int j = 0; j < 4; ++j) acc[i][j] = (f32x4){0.f, 0.f, 0.f, 0.f};

    for (int kt = 0; kt < K; kt += 32) {
        __syncthreads();
#pragma unroll
        for (int it = 0; it < 2; ++it) {
            int r = r0 + it * 64;
            *reinterpret_cast<uint4*>(&As[r][c80]) =
                *reinterpret_cast<const uint4*>(A + (size_t)(mBase + r) * K + kt + c80);
            *reinterpret_cast<uint4*>(&Bs[r][c80]) =
                *reinterpret_cast<const uint4*>(Bw + (size_t)(nBase + r) * K + kt + c80);
        }
        __syncthreads();
        bf16x8 af[4], bfr[4];
#pragma unroll
        for (int i = 0; i < 4; ++i) {
            af[i]  = *reinterpret_cast<const bf16x8*>(&As[wr + i * 16 + lr][lk]);
            bfr[i] = *reinterpret_cast<const bf16x8*>(&Bs[wc + i * 16 + lr][lk]);
        }
#pragma unroll
        for (int i = 0; i < 4; ++i)
#pragma unroll
            for (int j = 0; j < 4; ++j)
                acc[i][j] = __builtin_amdgcn_mfma_f32_16x16x32_bf16(
                    af[i], bfr[j], acc[i][j], 0, 0, 0);
    }

#pragma unroll
    for (int i = 0; i < 4; ++i)
#pragma unroll
        for (int j = 0; j < 4; ++j)
#pragma unroll
            for (int v = 0; v < 4; ++v) {
                const int row = mBase + wr + i * 16 + (lane >> 4) * 4 + v;
                const int col = nBase + wc + j * 16 + lr;
                if (OUT_BF16)
                    ((__hip_bfloat16*)Cv)[(size_t)row * N + col] =
                        __float2bfloat16(acc[i][j][v]);
                else
                    ((float*)Cv)[(size_t)row * N + col] = acc[i][j][v];
            }
}

// ---------------- flash attention, 4 waves x 32 q-rows, KVBLK=64 ----------------
// Swapped QK^T (mfma(K,Q) -> S^T): lane owns q = lane&31 entirely.
// K in LDS XOR-swizzled (byte ^= (row&7)<<4), staged with pre-swizzled global src.
// V in LDS transposed+swizzled via packed b32 writes (conflict-free).
// P -> bf16 B-frags in-register via pack + permlane32_swap. O^T accumulated.
__global__ __launch_bounds__(256) void attn_kernel(
    const __hip_bfloat16* __restrict__ QKV,   // [B*S][3E], Q|K|V blocks of E cols
    __hip_bfloat16* __restrict__ O) {         // [B*S][E]
    __shared__ __align__(16) __hip_bfloat16 Kl[64][64];
    __shared__ __align__(16) __hip_bfloat16 Vt[64][64];

    const int t = threadIdx.x, w = t >> 6, lane = t & 63;
    const int lq = lane & 31, hi = lane >> 5;
    const int qb0 = blockIdx.x * 128;
    const int h = blockIdx.y, b = blockIdx.z;

    const size_t rb = (size_t)b * SEQ;
    const __hip_bfloat16* Qg = QKV + rb * RQKV + h * HDIM;
    const __hip_bfloat16* Kg = QKV + rb * RQKV + E_DIM + h * HDIM;
    const __hip_bfloat16* Vg = QKV + rb * RQKV + 2 * E_DIM + h * HDIM;

    const int qg = qb0 + w * 32 + lq;   // this lane's q row (within batch b)

    // Q fragments (B-operand layout: n=lane&31, k=(lane>>5)*8+j), 4 d-slices of 16
    bf16x8 aq[4];
#pragma unroll
    for (int d0 = 0; d0 < 4; ++d0)
        aq[d0] = *reinterpret_cast<const bf16x8*>(
            Qg + (size_t)qg * RQKV + d0 * 16 + hi * 8);

    f32x16 oa[2];   // O^T accumulator: d-blocks [0,32) and [32,64); col=q=lane&31
#pragma unroll
    for (int m = 0; m < 2; ++m)
#pragma unroll
        for (int r = 0; r < 16; ++r) oa[m][r] = 0.f;
    float m_run = -1e30f, l_run = 0.f;

    const int kst_row  = w * 16 + (lane >> 3);   // K staging row this lane fills
    const int kst_slot = lane & 7;               // 16B slot within row
    const int v_kp = t & 31;                     // V staging: key pair 2*v_kp,2*v_kp+1
    const int v_d0 = (t >> 5) * 8;               // V staging: d octet
    const float SC = 0.03125f;                   // 1/sqrt(E) = 1/32

    const int NT = blockIdx.x * 2 + 2;           // causal tiles of 64 keys
    for (int kt = 0; kt < NT; ++kt) {
        const int k0 = kt * 64;
        __syncthreads();   // previous tile's LDS reads done

        // --- stage K[64][64] swizzled: LDS[r][c16] = K[k0+r][c16 ^ ((r&7)<<4)] ---
#pragma unroll
        for (int i = 0; i < 2; ++i) {
            const int r = kst_row + i * 8;
            const char* src = (const char*)(Kg + (size_t)(k0 + r) * RQKV) +
                              ((kst_slot * 16) ^ ((r & 7) << 4));
            gload_lds16(src, &Kl[w * 16 + i * 8][0]);
        }
        // --- stage V transposed: Vt[d][k], byte ^= ((d&7)<<4), packed b32 writes ---
        {
            const __hip_bfloat16* vp = Vg + (size_t)(k0 + 2 * v_kp) * RQKV + v_d0;
            bf16x8 va = *reinterpret_cast<const bf16x8*>(vp);
            bf16x8 vb = *reinterpret_cast<const bf16x8*>(vp + RQKV);
#pragma unroll
            for (int j = 0; j < 8; ++j) {
                const int d = v_d0 + j;
                const unsigned wbits =
                    ((unsigned)(unsigned short)vb[j] << 16) |
                    (unsigned short)va[j];
                *reinterpret_cast<unsigned*>(
                    reinterpret_cast<char*>(&Vt[0][0]) + d * 128 +
                    ((v_kp * 4) ^ ((d & 7) << 4))) = wbits;
            }
        }
        __syncthreads();   // staging visible (compiler drains vmcnt/lgkmcnt)

        if (k0 <= qb0 + w * 32 + 31) {   // wave has at least one valid key
            // --- QK^T: S^T tiles (32 keys x 32 q), 2 key sub-tiles ---
            f32x16 sc2[2];
#pragma unroll
            for (int tt = 0; tt < 2; ++tt) {
#pragma unroll
                for (int r = 0; r < 16; ++r) sc2[tt][r] = 0.f;
                const int kr = tt * 32 + lq;
                const char* kbase =
                    reinterpret_cast<const char*>(&Kl[0][0]) + kr * 128;
                const int swz = (kr & 7) << 4;
#pragma unroll
                for (int d0 = 0; d0 < 4; ++d0) {
                    bf16x8 ak = *reinterpret_cast<const bf16x8*>(
                        kbase + ((d0 * 32 + hi * 16) ^ swz));
                    sc2[tt] = __builtin_amdgcn_mfma_f32_32x32x16_bf16(
                        ak, aq[d0], sc2[tt], 0, 0, 0);
                }
            }
            // --- causal mask (wave-uniform skip when tile fully valid) ---
            if (k0 + 63 > qb0 + w * 32) {
#pragma unroll
                for (int tt = 0; tt < 2; ++tt)
#pragma unroll
                    for (int r = 0; r < 16; ++r) {
                        const int kgl = k0 + tt * 32 +
                                        (r & 3) + 8 * (r >> 2) + 4 * hi;
                        if (kgl > qg) sc2[tt][r] = -1e30f;
                    }
            }
            // --- online softmax: in-lane over 32 + one xor-32 exchange ---
            float mt = sc2[0][0];
#pragma unroll
            for (int tt = 0; tt < 2; ++tt)
#pragma unroll
                for (int r = 0; r < 16; ++r) mt = fmaxf(mt, sc2[tt][r]);
            mt = fmaxf(mt, __shfl_xor(mt, 32));
            const float mn = fmaxf(m_run, mt);
            const float corr = __expf((m_run - mn) * SC);
            float rsum = 0.f;
#pragma unroll
            for (int tt = 0; tt < 2; ++tt)
#pragma unroll
                for (int r = 0; r < 16; ++r) {
                    const float p = __expf((sc2[tt][r] - mn) * SC);
                    sc2[tt][r] = p;
                    rsum += p;
                }
            rsum += __shfl_xor(rsum, 32);
            l_run = l_run * corr + rsum;
            m_run = mn;
            oa[0] *= corr;
            oa[1] *= corr;

            // --- P -> bf16 B-frags via pack + permlane32_swap; PV MFMA ---
#pragma unroll
            for (int tt = 0; tt < 2; ++tt)
#pragma unroll
                for (int sl = 0; sl < 2; ++sl) {
                    const int rbs = sl * 8;
                    const unsigned wA =
                        ((unsigned)bits_of(__float2bfloat16(sc2[tt][rbs + 1])) << 16) |
                        bits_of(__float2bfloat16(sc2[tt][rbs + 0]));
                    const unsigned wB =
                        ((unsigned)bits_of(__float2bfloat16(sc2[tt][rbs + 3])) << 16) |
                        bits_of(__float2bfloat16(sc2[tt][rbs + 2]));
                    const unsigned wC =
                        ((unsigned)bits_of(__float2bfloat16(sc2[tt][rbs + 5])) << 16) |
                        bits_of(__float2bfloat16(sc2[tt][rbs + 4]));
                    const unsigned wD =
                        ((unsigned)bits_of(__float2bfloat16(sc2[tt][rbs + 7])) << 16) |
                        bits_of(__float2bfloat16(sc2[tt][rbs + 6]));
                    const auto pA = __builtin_amdgcn_permlane32_swap(wA, wC, false, false);
                    const auto pB = __builtin_amdgcn_permlane32_swap(wB, wD, false, false);
                    union { unsigned u[4]; bf16x8 v; } pf;
                    pf.u[0] = pA[0]; pf.u[1] = pB[0];
                    pf.u[2] = pA[1]; pf.u[3] = pB[1];
                    const int ks = tt * 2 + sl;   // 16-key slice index
#pragma unroll
                    for (int m = 0; m < 2; ++m) {
                        const int dr = m * 32 + lq;
                        bf16x8 av = *reinterpret_cast<const bf16x8*>(
                            reinterpret_cast<const char*>(&Vt[0][0]) + dr * 128 +
                            ((ks * 32 + hi * 16) ^ ((dr & 7) << 4)));
                        oa[m] = __builtin_amdgcn_mfma_f32_32x32x16_bf16(
                            av, pf.v, oa[m], 0, 0, 0);
                    }
                }
        }
    }

    // --- epilogue: normalize, pack 4 bf16 (consecutive d) per 8B store ---
    const float inv = 1.f / l_run;
    __hip_bfloat16* Orow = O + (rb + qg) * E_DIM + h * HDIM;
#pragma unroll
    for (int m = 0; m < 2; ++m)
#pragma unroll
        for (int q4 = 0; q4 < 4; ++q4) {
            ushort4 pk;
            pk.x = bits_of(__float2bfloat16(oa[m][q4 * 4 + 0] * inv));
            pk.y = bits_of(__float2bfloat16(oa[m][q4 * 4 + 1] * inv));
            pk.z = bits_of(__float2bfloat16(oa[m][q4 * 4 + 2] * inv));
            pk.w = bits_of(__float2bfloat16(oa[m][q4 * 4 + 3] * inv));
            *reinterpret_cast<ushort4*>(Orow + m * 32 + q4 * 8 + 4 * hi) = pk;
        }
}

// ---------------- launch ----------------
extern "C" void kernel_launch(void* const* d_in, const int* in_sizes, int n_in,
                              void* d_out, int out_size, void* d_ws, size_t ws_size,
                              hipStream_t stream) {
    const float* x  = (const float*)d_in[0];
    const float* wq = (const float*)d_in[1];
    const float* wk = (const float*)d_in[2];
    const float* wv = (const float*)d_in[3];
    const float* wo = (const float*)d_in[4];

    const size_t SZ_X = (size_t)BATCH * SEQ * E_DIM;   // 8388608
    const size_t SZ_W = (size_t)E_DIM * E_DIM;         // 1048576

    char* p = (char*)d_ws;
    __hip_bfloat16* xb    = (__hip_bfloat16*)p; p += SZ_X * 2;
    __hip_bfloat16* wqkvb = (__hip_bfloat16*)p; p += 3 * SZ_W * 2;   // [3E][E]
    __hip_bfloat16* wob   = (__hip_bfloat16*)p; p += SZ_W * 2;
    __hip_bfloat16* QKVb  = (__hip_bfloat16*)p; p += SZ_X * 3 * 2;   // [M][3E]
    __hip_bfloat16* attb  = (__hip_bfloat16*)p; p += SZ_X * 2;

    cast_kernel<<<(int)(SZ_X / 4 / 256), 256, 0, stream>>>(x, xb, (int)(SZ_X / 4));
    cast_kernel<<<(int)(SZ_W / 4 / 256), 256, 0, stream>>>(wq, wqkvb, (int)(SZ_W / 4));
    cast_kernel<<<(int)(SZ_W / 4 / 256), 256, 0, stream>>>(wk, wqkvb + SZ_W, (int)(SZ_W / 4));
    cast_kernel<<<(int)(SZ_W / 4 / 256), 256, 0, stream>>>(wv, wqkvb + 2 * SZ_W, (int)(SZ_W / 4));
    cast_kernel<<<(int)(SZ_W / 4 / 256), 256, 0, stream>>>(wo, wob, (int)(SZ_W / 4));

    const int M = BATCH * SEQ;  // 8192
    // fused QKV projection: [M][E] x [3E][E]^T -> [M][3E]
    gemm_bt<1><<<dim3(RQKV / 128, M / 128), 256, 0, stream>>>(
        xb, wqkvb, QKVb, M, RQKV, E_DIM);

    attn_kernel<<<dim3(SEQ / 128, NHEAD, BATCH), 256, 0, stream>>>(QKVb, attb);

    gemm_bt<0><<<dim3(E_DIM / 128, M / 128), 256, 0, stream>>>(
        attb, wob, d_out, M, E_DIM, E_DIM);
}